// Round 1
// baseline (1070.774 us; speedup 1.0000x reference)
//
#include <hip/hip_runtime.h>
#include <cstdint>
#include <cstddef>

// ---------------------------------------------------------------------------
// GCN 3-layer forward: gcnconv -> BN -> relu -> gcnconv -> BN -> relu ->
// gcnconv -> log_softmax.  f32 throughout.
// Strategy: build CSR (incoming edges per dst) once per call, then per-layer:
//   gemm (fused BN+relu of previous layer on A-load) -> per-node register
//   aggregation (one wave per node) -> column stats.
// ---------------------------------------------------------------------------

#define DH 128

__global__ __launch_bounds__(256) void count_deg(const int* __restrict__ dst,
                                                 int* __restrict__ cnt, int E) {
    int e = blockIdx.x * 256 + threadIdx.x;
    if (e < E) atomicAdd(&cnt[dst[e]], 1);
}

__global__ __launch_bounds__(256) void compute_dinv(const int* __restrict__ cnt,
                                                    float* __restrict__ dinv, int n) {
    int i = blockIdx.x * 256 + threadIdx.x;
    if (i < n) dinv[i] = rsqrtf((float)(cnt[i] + 1));  // +1 self loop
}

__global__ __launch_bounds__(256) void scan1(const int* __restrict__ cnt,
                                             int* __restrict__ offs,
                                             int* __restrict__ bsums, int n) {
    __shared__ int s[256];
    int tx = threadIdx.x;
    int i = blockIdx.x * 256 + tx;
    int v = (i < n) ? cnt[i] : 0;
    s[tx] = v;
    __syncthreads();
    for (int off = 1; off < 256; off <<= 1) {
        int t = (tx >= off) ? s[tx - off] : 0;
        __syncthreads();
        s[tx] += t;
        __syncthreads();
    }
    if (i < n) offs[i] = s[tx] - v;           // exclusive within block
    if (tx == 255) bsums[blockIdx.x] = s[255];
}

__global__ void scan2(const int* __restrict__ bsums, int* __restrict__ bscan, int nb) {
    __shared__ int s[512];
    int tx = threadIdx.x;
    int v = (tx < nb) ? bsums[tx] : 0;
    s[tx] = v;
    __syncthreads();
    for (int off = 1; off < 512; off <<= 1) {
        int t = (tx >= off) ? s[tx - off] : 0;
        __syncthreads();
        s[tx] += t;
        __syncthreads();
    }
    if (tx < nb) bscan[tx] = s[tx] - v;       // exclusive block offsets
}

__global__ __launch_bounds__(256) void scan3(int* __restrict__ offs,
                                             const int* __restrict__ bscan,
                                             int n, int E) {
    int i = blockIdx.x * 256 + threadIdx.x;
    if (i < n) offs[i] += bscan[blockIdx.x];
    if (i == 0) offs[n] = E;
}

__global__ __launch_bounds__(256) void fill_csr(const int* __restrict__ src,
                                                const int* __restrict__ dst,
                                                const int* __restrict__ offs,
                                                int* __restrict__ cursor,
                                                int* __restrict__ csr, int E) {
    int e = blockIdx.x * 256 + threadIdx.x;
    if (e < E) {
        int d = dst[e];
        int pos = offs[d] + atomicAdd(&cursor[d], 1);
        csr[pos] = src[e];
    }
}

#define FMA4(acc, a)                                              \
    acc.x += a.x * w0.x + a.y * w1.x + a.z * w2.x + a.w * w3.x;   \
    acc.y += a.x * w0.y + a.y * w1.y + a.z * w2.y + a.w * w3.y;   \
    acc.z += a.x * w0.z + a.y * w1.z + a.z * w2.z + a.w * w3.z;   \
    acc.w += a.x * w0.w + a.y * w1.w + a.z * w2.w + a.w * w3.w;

// C[n x 128] = bnrelu(A[n x 128]) @ W[128 x 128].  32 rows per block.
__global__ __launch_bounds__(256) void gemm128(const float* __restrict__ A,
                                               const float* __restrict__ W,
                                               float* __restrict__ C, int n,
                                               const float* __restrict__ scale,
                                               const float* __restrict__ shift) {
    __shared__ float Wls[128 * 128];
    __shared__ float Als[32 * 128];
    int tx = threadIdx.x;
    {   // stage W (4096 float4)
        float4* Wd = (float4*)Wls;
        const float4* Wg = (const float4*)W;
#pragma unroll
        for (int i = 0; i < 16; i++) Wd[tx + 256 * i] = Wg[tx + 256 * i];
    }
    int row0 = blockIdx.x * 32;
    {   // stage A tile (1024 float4) with optional fused BN+relu
        float4* Ad = (float4*)Als;
        const float4* Ag = (const float4*)(A + (size_t)row0 * 128);
        if (scale) {
            const float4* sc4 = (const float4*)scale;
            const float4* sh4 = (const float4*)shift;
#pragma unroll
            for (int j = 0; j < 4; j++) {
                int idx = tx + 256 * j;
                int kq = idx & 31;
                float4 v = Ag[idx];
                float4 s = sc4[kq], h = sh4[kq];
                v.x = fmaxf(0.f, v.x * s.x + h.x);
                v.y = fmaxf(0.f, v.y * s.y + h.y);
                v.z = fmaxf(0.f, v.z * s.z + h.z);
                v.w = fmaxf(0.f, v.w * s.w + h.w);
                Ad[idx] = v;
            }
        } else {
#pragma unroll
            for (int j = 0; j < 4; j++) Ad[tx + 256 * j] = Ag[tx + 256 * j];
        }
    }
    __syncthreads();

    int cq = tx & 31;   // column quad (4 cols)
    int rr = tx >> 5;   // row group (4 rows)
    const float4* Wls4 = (const float4*)Wls;
    const float4* Als4 = (const float4*)Als;
    float4 acc0 = {0, 0, 0, 0}, acc1 = {0, 0, 0, 0}, acc2 = {0, 0, 0, 0}, acc3 = {0, 0, 0, 0};
#pragma unroll 8
    for (int kq = 0; kq < 32; kq++) {
        float4 a0 = Als4[(rr * 4 + 0) * 32 + kq];
        float4 a1 = Als4[(rr * 4 + 1) * 32 + kq];
        float4 a2 = Als4[(rr * 4 + 2) * 32 + kq];
        float4 a3 = Als4[(rr * 4 + 3) * 32 + kq];
        float4 w0 = Wls4[(kq * 4 + 0) * 32 + cq];
        float4 w1 = Wls4[(kq * 4 + 1) * 32 + cq];
        float4 w2 = Wls4[(kq * 4 + 2) * 32 + cq];
        float4 w3 = Wls4[(kq * 4 + 3) * 32 + cq];
        FMA4(acc0, a0)
        FMA4(acc1, a1)
        FMA4(acc2, a2)
        FMA4(acc3, a3)
    }
    float4* Cp = (float4*)(C + (size_t)row0 * 128);
    Cp[(rr * 4 + 0) * 32 + cq] = acc0;
    Cp[(rr * 4 + 1) * 32 + cq] = acc1;
    Cp[(rr * 4 + 2) * 32 + cq] = acc2;
    Cp[(rr * 4 + 3) * 32 + cq] = acc3;
}

// C[n x 40] = bnrelu(A[n x 128]) @ W[128 x 40].  32 rows per block.
__global__ __launch_bounds__(256) void gemm40(const float* __restrict__ A,
                                              const float* __restrict__ W,
                                              float* __restrict__ C, int n,
                                              const float* __restrict__ scale,
                                              const float* __restrict__ shift) {
    __shared__ float Wls[128 * 40];
    __shared__ float Als[32 * 128];
    int tx = threadIdx.x;
    {
        float4* Wd = (float4*)Wls;
        const float4* Wg = (const float4*)W;
#pragma unroll
        for (int i = 0; i < 5; i++) Wd[tx + 256 * i] = Wg[tx + 256 * i];
    }
    int row0 = blockIdx.x * 32;
    {
        float4* Ad = (float4*)Als;
        const float4* Ag = (const float4*)(A + (size_t)row0 * 128);
        const float4* sc4 = (const float4*)scale;
        const float4* sh4 = (const float4*)shift;
#pragma unroll
        for (int j = 0; j < 4; j++) {
            int idx = tx + 256 * j;
            int kq = idx & 31;
            float4 v = Ag[idx];
            float4 s = sc4[kq], h = sh4[kq];
            v.x = fmaxf(0.f, v.x * s.x + h.x);
            v.y = fmaxf(0.f, v.y * s.y + h.y);
            v.z = fmaxf(0.f, v.z * s.z + h.z);
            v.w = fmaxf(0.f, v.w * s.w + h.w);
            Ad[idx] = v;
        }
    }
    __syncthreads();

    int cq = tx & 15;   // only cq<10 active
    int rg = tx >> 4;   // 16 row groups x 2 rows
    const float4* Wls4 = (const float4*)Wls;
    const float4* Als4 = (const float4*)Als;
    if (cq < 10) {
        float4 acc0 = {0, 0, 0, 0}, acc1 = {0, 0, 0, 0};
#pragma unroll 8
        for (int kq = 0; kq < 32; kq++) {
            float4 a0 = Als4[(rg * 2 + 0) * 32 + kq];
            float4 a1 = Als4[(rg * 2 + 1) * 32 + kq];
            float4 w0 = Wls4[(kq * 4 + 0) * 10 + cq];
            float4 w1 = Wls4[(kq * 4 + 1) * 10 + cq];
            float4 w2 = Wls4[(kq * 4 + 2) * 10 + cq];
            float4 w3 = Wls4[(kq * 4 + 3) * 10 + cq];
            FMA4(acc0, a0)
            FMA4(acc1, a1)
        }
        int r0 = row0 + rg * 2;
        *(float4*)(C + (size_t)r0 * 40 + cq * 4) = acc0;
        *(float4*)(C + (size_t)(r0 + 1) * 40 + cq * 4) = acc1;
    }
}

// out[n][c] = sum_{s in N(n)} h[s][c]*dinv[s]*dinv[n] + h[n][c]*dinv[n]^2 + bias[c]
// one wave per node, 2 cols per lane.
__global__ __launch_bounds__(256) void agg128(const float* __restrict__ h,
                                              const int* __restrict__ csr,
                                              const int* __restrict__ offs,
                                              const float* __restrict__ dinv,
                                              const float* __restrict__ bias,
                                              float* __restrict__ out, int n) {
    int wid = (blockIdx.x * 256 + threadIdx.x) >> 6;
    int lane = threadIdx.x & 63;
    if (wid >= n) return;
    float di = dinv[wid];
    const float2* hp = (const float2*)h;
    float2 v = hp[(size_t)wid * 64 + lane];
    float sl = di * di;
    float ax = v.x * sl, ay = v.y * sl;
    int e0 = offs[wid], e1 = offs[wid + 1];
    for (int e = e0; e < e1; e++) {
        int s = csr[e];
        float w = dinv[s] * di;
        float2 u = hp[(size_t)s * 64 + lane];
        ax += u.x * w;
        ay += u.y * w;
    }
    float2 b = ((const float2*)bias)[lane];
    float2 r;
    r.x = ax + b.x;
    r.y = ay + b.y;
    ((float2*)out)[(size_t)wid * 64 + lane] = r;
}

// same for 40 cols, fused bias + log_softmax epilogue.
__global__ __launch_bounds__(256) void agg40_lsm(const float* __restrict__ h,
                                                 const int* __restrict__ csr,
                                                 const int* __restrict__ offs,
                                                 const float* __restrict__ dinv,
                                                 const float* __restrict__ bias,
                                                 float* __restrict__ out, int n) {
    int wid = (blockIdx.x * 256 + threadIdx.x) >> 6;
    int lane = threadIdx.x & 63;
    if (wid >= n) return;
    float di = dinv[wid];
    float acc = 0.f;
    if (lane < 40) acc = h[(size_t)wid * 40 + lane] * di * di;
    int e0 = offs[wid], e1 = offs[wid + 1];
    for (int e = e0; e < e1; e++) {
        int s = csr[e];
        float w = dinv[s] * di;
        if (lane < 40) acc += h[(size_t)s * 40 + lane] * w;
    }
    float val = (lane < 40) ? acc + bias[lane] : -1e30f;
    float m = val;
    for (int off = 32; off; off >>= 1) m = fmaxf(m, __shfl_xor(m, off, 64));
    float ex = (lane < 40) ? expf(val - m) : 0.f;
    float ssum = ex;
    for (int off = 32; off; off >>= 1) ssum += __shfl_xor(ssum, off, 64);
    float lg = logf(ssum);
    if (lane < 40) out[(size_t)wid * 40 + lane] = val - m - lg;
}

// per-block column partial sums/sumsq (deterministic, no atomics)
__global__ __launch_bounds__(256) void stats_k(const float* __restrict__ h,
                                               float* __restrict__ psum,
                                               float* __restrict__ psq, int n) {
    int c = threadIdx.x & 127;
    int half = threadIdx.x >> 7;
    float s = 0.f, q = 0.f;
    for (int r = blockIdx.x * 2 + half; r < n; r += gridDim.x * 2) {
        float v = h[(size_t)r * 128 + c];
        s += v;
        q += v * v;
    }
    __shared__ float ls[256], lq[256];
    ls[threadIdx.x] = s;
    lq[threadIdx.x] = q;
    __syncthreads();
    if (threadIdx.x < 128) {
        psum[blockIdx.x * 128 + threadIdx.x] = ls[threadIdx.x] + ls[threadIdx.x + 128];
        psq[blockIdx.x * 128 + threadIdx.x] = lq[threadIdx.x] + lq[threadIdx.x + 128];
    }
}

__global__ void finalize_stats(const float* __restrict__ psum,
                               const float* __restrict__ psq,
                               const float* __restrict__ g,
                               const float* __restrict__ be,
                               float* __restrict__ scale,
                               float* __restrict__ shift, int nb, float invN) {
    int c = threadIdx.x;  // 128 threads
    float s = 0.f, q = 0.f;
    for (int b = 0; b < nb; b++) {
        s += psum[b * 128 + c];
        q += psq[b * 128 + c];
    }
    float mu = s * invN;
    float var = q * invN - mu * mu;
    float sc = g[c] * rsqrtf(var + 1e-5f);
    scale[c] = sc;
    shift[c] = be[c] - mu * sc;
}

extern "C" void kernel_launch(void* const* d_in, const int* in_sizes, int n_in,
                              void* d_out, int out_size, void* d_ws, size_t ws_size,
                              hipStream_t stream) {
    const float* x   = (const float*)d_in[0];
    const float* W1  = (const float*)d_in[1];
    const float* b1  = (const float*)d_in[2];
    const float* W2  = (const float*)d_in[3];
    const float* b2  = (const float*)d_in[4];
    const float* W3  = (const float*)d_in[5];
    const float* b3  = (const float*)d_in[6];
    const float* g1  = (const float*)d_in[7];
    const float* be1 = (const float*)d_in[8];
    const float* g2  = (const float*)d_in[9];
    const float* be2 = (const float*)d_in[10];
    const int*   ei  = (const int*)d_in[11];

    int n = in_sizes[0] / 128;
    int E = in_sizes[11] / 2;
    const int* src = ei;
    const int* dst = ei + E;

    char* p = (char*)d_ws;
    size_t off = 0;
    auto alloc = [&](size_t bytes) -> void* {
        off = (off + 255) & ~(size_t)255;
        void* r = p + off;
        off += bytes;
        return r;
    };
    float* hA     = (float*)alloc((size_t)n * 128 * 4);
    float* hB     = (float*)alloc((size_t)n * 128 * 4);
    float* dinv   = (float*)alloc((size_t)n * 4);
    int*   cnt    = (int*)alloc((size_t)2 * n * 4);  // cnt + cursor contiguous
    int*   cursor = cnt + n;
    int*   offs   = (int*)alloc((size_t)(n + 1) * 4);
    int*   bsums  = (int*)alloc(512 * 4);
    int*   bscan  = (int*)alloc(512 * 4);
    int*   csr    = (int*)alloc((size_t)E * 4);
    float* psum   = (float*)alloc(256 * 128 * 4);
    float* psq    = (float*)alloc(256 * 128 * 4);
    float* scale  = (float*)alloc(128 * 4);
    float* shift  = (float*)alloc(128 * 4);
    (void)ws_size;

    int nbE = (E + 255) / 256;
    int nbN = (n + 255) / 256;          // 391
    int gGemm = (n + 31) / 32;          // 3125
    int gAgg = (n * 64 + 255) / 256;    // 25000
    float invN = 1.0f / (float)n;

    hipMemsetAsync(cnt, 0, (size_t)2 * n * 4, stream);

    count_deg<<<nbE, 256, 0, stream>>>(dst, cnt, E);
    compute_dinv<<<nbN, 256, 0, stream>>>(cnt, dinv, n);
    scan1<<<nbN, 256, 0, stream>>>(cnt, offs, bsums, n);
    scan2<<<1, 512, 0, stream>>>(bsums, bscan, nbN);
    scan3<<<nbN, 256, 0, stream>>>(offs, bscan, n, E);
    fill_csr<<<nbE, 256, 0, stream>>>(src, dst, offs, cursor, csr, E);

    // layer 1
    gemm128<<<gGemm, 256, 0, stream>>>(x, W1, hA, n, nullptr, nullptr);
    agg128<<<gAgg, 256, 0, stream>>>(hA, csr, offs, dinv, b1, hB, n);
    stats_k<<<256, 256, 0, stream>>>(hB, psum, psq, n);
    finalize_stats<<<1, 128, 0, stream>>>(psum, psq, g1, be1, scale, shift, 256, invN);

    // layer 2 (BN1+relu fused into gemm A-load)
    gemm128<<<gGemm, 256, 0, stream>>>(hB, W2, hA, n, scale, shift);
    agg128<<<gAgg, 256, 0, stream>>>(hA, csr, offs, dinv, b2, hB, n);
    stats_k<<<256, 256, 0, stream>>>(hB, psum, psq, n);
    finalize_stats<<<1, 128, 0, stream>>>(psum, psq, g2, be2, scale, shift, 256, invN);

    // layer 3 (BN2+relu fused) + aggregation + log_softmax
    gemm40<<<gGemm, 256, 0, stream>>>(hB, W3, hA, n, scale, shift);
    agg40_lsm<<<gAgg, 256, 0, stream>>>(hA, csr, offs, dinv, b3, (float*)d_out, n);
}

// Round 2
// 921.040 us; speedup vs baseline: 1.1626x; 1.1626x over previous
//
#include <hip/hip_runtime.h>
#include <cstdint>
#include <cstddef>

// ---------------------------------------------------------------------------
// GCN 3-layer forward, f32 compute with bf16 message storage.
// gemm epilogue pre-scales rows by dinv[row] so aggregation is a pure sum:
//   out[d] = dinv[d] * (sum_{s in N(d)} hs[s] + hs[d]) + bias
// ---------------------------------------------------------------------------

typedef unsigned int uint32;
typedef unsigned short ushort16;

__device__ inline float bl(uint32 u) { uint32 v = u << 16; return __builtin_bit_cast(float, v); }
__device__ inline float bh(uint32 u) { uint32 v = u & 0xffff0000u; return __builtin_bit_cast(float, v); }
__device__ inline uint32 f2b(float f) {   // RNE f32 -> bf16 bits
    uint32 u = __builtin_bit_cast(uint32, f);
    return (u + 0x7fffu + ((u >> 16) & 1u)) >> 16;
}
__device__ inline uint32 pack2(float x, float y) { return f2b(x) | (f2b(y) << 16); }

__global__ __launch_bounds__(256) void count_deg(const int* __restrict__ dst,
                                                 int* __restrict__ cnt, int E) {
    int e = blockIdx.x * 256 + threadIdx.x;
    if (e < E) atomicAdd(&cnt[dst[e]], 1);
}

__global__ __launch_bounds__(256) void compute_dinv(const int* __restrict__ cnt,
                                                    float* __restrict__ dinv, int n) {
    int i = blockIdx.x * 256 + threadIdx.x;
    if (i < n) dinv[i] = rsqrtf((float)(cnt[i] + 1));  // +1 self loop
}

__global__ __launch_bounds__(256) void scan1(const int* __restrict__ cnt,
                                             int* __restrict__ offs,
                                             int* __restrict__ bsums, int n) {
    __shared__ int s[256];
    int tx = threadIdx.x;
    int i = blockIdx.x * 256 + tx;
    int v = (i < n) ? cnt[i] : 0;
    s[tx] = v;
    __syncthreads();
    for (int off = 1; off < 256; off <<= 1) {
        int t = (tx >= off) ? s[tx - off] : 0;
        __syncthreads();
        s[tx] += t;
        __syncthreads();
    }
    if (i < n) offs[i] = s[tx] - v;
    if (tx == 255) bsums[blockIdx.x] = s[255];
}

__global__ void scan2(const int* __restrict__ bsums, int* __restrict__ bscan, int nb) {
    __shared__ int s[512];
    int tx = threadIdx.x;
    int v = (tx < nb) ? bsums[tx] : 0;
    s[tx] = v;
    __syncthreads();
    for (int off = 1; off < 512; off <<= 1) {
        int t = (tx >= off) ? s[tx - off] : 0;
        __syncthreads();
        s[tx] += t;
        __syncthreads();
    }
    if (tx < nb) bscan[tx] = s[tx] - v;
}

__global__ __launch_bounds__(256) void scan3(int* __restrict__ offs,
                                             const int* __restrict__ bscan,
                                             int n, int E) {
    int i = blockIdx.x * 256 + threadIdx.x;
    if (i < n) offs[i] += bscan[blockIdx.x];
    if (i == 0) offs[n] = E;
}

__global__ __launch_bounds__(256) void fill_csr(const int* __restrict__ src,
                                                const int* __restrict__ dst,
                                                const int* __restrict__ offs,
                                                int* __restrict__ cursor,
                                                int* __restrict__ csr, int E) {
    int e = blockIdx.x * 256 + threadIdx.x;
    if (e < E) {
        int d = dst[e];
        int pos = offs[d] + atomicAdd(&cursor[d], 1);
        csr[pos] = src[e];
    }
}

#define FMA4(acc, a)                                              \
    acc.x += a.x * w0.x + a.y * w1.x + a.z * w2.x + a.w * w3.x;   \
    acc.y += a.x * w0.y + a.y * w1.y + a.z * w2.y + a.w * w3.y;   \
    acc.z += a.x * w0.z + a.y * w1.z + a.z * w2.z + a.w * w3.z;   \
    acc.w += a.x * w0.w + a.y * w1.w + a.z * w2.w + a.w * w3.w;

// C[r][c] (bf16, packed pairs) = bnrelu(A[r][:]) @ W[:, c] * dinv[r]
template <bool ABF16, bool BN>
__global__ __launch_bounds__(256) void gemm128_k(const void* __restrict__ Av,
                                                 const float* __restrict__ W,
                                                 uint32* __restrict__ C,
                                                 const float* __restrict__ dinv, int n,
                                                 const float* __restrict__ scale,
                                                 const float* __restrict__ shift) {
    __shared__ float Wls[128 * 128];
    __shared__ float Als[32 * 128];
    int tx = threadIdx.x;
    {
        float4* Wd = (float4*)Wls;
        const float4* Wg = (const float4*)W;
#pragma unroll
        for (int i = 0; i < 16; i++) Wd[tx + 256 * i] = Wg[tx + 256 * i];
    }
    int row0 = blockIdx.x * 32;
    if (ABF16) {
        const uint4* Ag = (const uint4*)((const ushort16*)Av + (size_t)row0 * 128);
#pragma unroll
        for (int t = tx; t < 512; t += 256) {   // 512 chunks of 8 bf16
            uint4 u = Ag[t];
            int row = t >> 4, c0 = (t & 15) * 8;
            float f[8] = {bl(u.x), bh(u.x), bl(u.y), bh(u.y),
                          bl(u.z), bh(u.z), bl(u.w), bh(u.w)};
#pragma unroll
            for (int j = 0; j < 8; j++) {
                float v = f[j];
                if (BN) v = fmaxf(0.f, v * scale[c0 + j] + shift[c0 + j]);
                Als[row * 128 + c0 + j] = v;
            }
        }
    } else {
        float4* Ad = (float4*)Als;
        const float4* Ag = (const float4*)((const float*)Av + (size_t)row0 * 128);
#pragma unroll
        for (int j = 0; j < 4; j++) Ad[tx + 256 * j] = Ag[tx + 256 * j];
    }
    __syncthreads();

    int cq = tx & 31;
    int rr = tx >> 5;
    const float4* Wls4 = (const float4*)Wls;
    const float4* Als4 = (const float4*)Als;
    float4 acc0 = {0, 0, 0, 0}, acc1 = {0, 0, 0, 0}, acc2 = {0, 0, 0, 0}, acc3 = {0, 0, 0, 0};
#pragma unroll 8
    for (int kq = 0; kq < 32; kq++) {
        float4 a0 = Als4[(rr * 4 + 0) * 32 + kq];
        float4 a1 = Als4[(rr * 4 + 1) * 32 + kq];
        float4 a2 = Als4[(rr * 4 + 2) * 32 + kq];
        float4 a3 = Als4[(rr * 4 + 3) * 32 + kq];
        float4 w0 = Wls4[(kq * 4 + 0) * 32 + cq];
        float4 w1 = Wls4[(kq * 4 + 1) * 32 + cq];
        float4 w2 = Wls4[(kq * 4 + 2) * 32 + cq];
        float4 w3 = Wls4[(kq * 4 + 3) * 32 + cq];
        FMA4(acc0, a0)
        FMA4(acc1, a1)
        FMA4(acc2, a2)
        FMA4(acc3, a3)
    }
    uint2* Cp = (uint2*)C;   // row = 32 uint2
#pragma unroll
    for (int i = 0; i < 4; i++) {
        float4 a = (i == 0) ? acc0 : (i == 1) ? acc1 : (i == 2) ? acc2 : acc3;
        int r = row0 + rr * 4 + i;
        float dv = dinv[r];
        uint2 o;
        o.x = pack2(a.x * dv, a.y * dv);
        o.y = pack2(a.z * dv, a.w * dv);
        Cp[(size_t)r * 32 + cq] = o;
    }
}

// C[n x 40] bf16 = bnrelu(A bf16) @ W[128 x 40] * dinv[r]
__global__ __launch_bounds__(256) void gemm40(const ushort16* __restrict__ A,
                                              const float* __restrict__ W,
                                              uint32* __restrict__ C,
                                              const float* __restrict__ dinv, int n,
                                              const float* __restrict__ scale,
                                              const float* __restrict__ shift) {
    __shared__ float Wls[128 * 40];
    __shared__ float Als[32 * 128];
    int tx = threadIdx.x;
    {
        float4* Wd = (float4*)Wls;
        const float4* Wg = (const float4*)W;
#pragma unroll
        for (int i = 0; i < 5; i++) Wd[tx + 256 * i] = Wg[tx + 256 * i];
    }
    int row0 = blockIdx.x * 32;
    {
        const uint4* Ag = (const uint4*)(A + (size_t)row0 * 128);
#pragma unroll
        for (int t = tx; t < 512; t += 256) {
            uint4 u = Ag[t];
            int row = t >> 4, c0 = (t & 15) * 8;
            float f[8] = {bl(u.x), bh(u.x), bl(u.y), bh(u.y),
                          bl(u.z), bh(u.z), bl(u.w), bh(u.w)};
#pragma unroll
            for (int j = 0; j < 8; j++) {
                float v = f[j];
                v = fmaxf(0.f, v * scale[c0 + j] + shift[c0 + j]);
                Als[row * 128 + c0 + j] = v;
            }
        }
    }
    __syncthreads();

    int cq = tx & 15;   // only cq<10 active
    int rg = tx >> 4;
    const float4* Wls4 = (const float4*)Wls;
    const float4* Als4 = (const float4*)Als;
    if (cq < 10) {
        float4 acc0 = {0, 0, 0, 0}, acc1 = {0, 0, 0, 0};
#pragma unroll 8
        for (int kq = 0; kq < 32; kq++) {
            float4 a0 = Als4[(rg * 2 + 0) * 32 + kq];
            float4 a1 = Als4[(rg * 2 + 1) * 32 + kq];
            float4 w0 = Wls4[(kq * 4 + 0) * 10 + cq];
            float4 w1 = Wls4[(kq * 4 + 1) * 10 + cq];
            float4 w2 = Wls4[(kq * 4 + 2) * 10 + cq];
            float4 w3 = Wls4[(kq * 4 + 3) * 10 + cq];
            FMA4(acc0, a0)
            FMA4(acc1, a1)
        }
        uint2* Cp = (uint2*)C;   // row = 10 uint2
        int r0 = row0 + rg * 2;
        float d0 = dinv[r0], d1 = dinv[r0 + 1];
        uint2 o0, o1;
        o0.x = pack2(acc0.x * d0, acc0.y * d0);
        o0.y = pack2(acc0.z * d0, acc0.w * d0);
        o1.x = pack2(acc1.x * d1, acc1.y * d1);
        o1.y = pack2(acc1.z * d1, acc1.w * d1);
        Cp[(size_t)r0 * 10 + cq] = o0;
        Cp[(size_t)(r0 + 1) * 10 + cq] = o1;
    }
}

// out[d] = pack( dinv[d] * (sum_{s in N(d)} hs[s] + hs[d]) + bias ), bf16 128 cols
__global__ __launch_bounds__(256) void agg128(const uint32* __restrict__ h,
                                              const int* __restrict__ csr,
                                              const int* __restrict__ offs,
                                              const float* __restrict__ dinv,
                                              const float* __restrict__ bias,
                                              uint32* __restrict__ out, int n) {
    int wid = (blockIdx.x * 256 + threadIdx.x) >> 6;
    int lane = threadIdx.x & 63;
    if (wid >= n) return;
    uint32 self = h[(size_t)wid * 64 + lane];
    float ax = bl(self), ay = bh(self);
    int e0 = offs[wid], e1 = offs[wid + 1];
    int e = e0;
    while (e < e1) {
        int cnt = e1 - e;
        if (cnt > 64) cnt = 64;
        int sl = (lane < cnt) ? csr[e + lane] : 0;
        for (int j = 0; j < cnt; j++) {
            int s = __shfl(sl, j, 64);
            uint32 u = h[(size_t)s * 64 + lane];
            ax += bl(u);
            ay += bh(u);
        }
        e += cnt;
    }
    float di = dinv[wid];
    float2 b = ((const float2*)bias)[lane];
    out[(size_t)wid * 64 + lane] = pack2(ax * di + b.x, ay * di + b.y);
}

// 40-col aggregation + bias + log_softmax, bf16 in, f32 out
__global__ __launch_bounds__(256) void agg40_lsm(const uint32* __restrict__ h,
                                                 const int* __restrict__ csr,
                                                 const int* __restrict__ offs,
                                                 const float* __restrict__ dinv,
                                                 const float* __restrict__ bias,
                                                 float* __restrict__ out, int n) {
    int wid = (blockIdx.x * 256 + threadIdx.x) >> 6;
    int lane = threadIdx.x & 63;
    if (wid >= n) return;
    bool act = lane < 20;
    float vx = 0.f, vy = 0.f;
    if (act) {
        uint32 u = h[(size_t)wid * 20 + lane];
        vx = bl(u);
        vy = bh(u);
    }
    int e0 = offs[wid], e1 = offs[wid + 1];
    int e = e0;
    while (e < e1) {
        int cnt = e1 - e;
        if (cnt > 64) cnt = 64;
        int sl = (lane < cnt) ? csr[e + lane] : 0;
        for (int j = 0; j < cnt; j++) {
            int s = __shfl(sl, j, 64);
            if (act) {
                uint32 u = h[(size_t)s * 20 + lane];
                vx += bl(u);
                vy += bh(u);
            }
        }
        e += cnt;
    }
    float di = dinv[wid];
    float v0 = -1e30f, v1 = -1e30f;
    if (act) {
        v0 = vx * di + bias[2 * lane];
        v1 = vy * di + bias[2 * lane + 1];
    }
    float m = fmaxf(v0, v1);
    for (int off = 16; off; off >>= 1) m = fmaxf(m, __shfl_xor(m, off, 64));
    float ss = act ? (expf(v0 - m) + expf(v1 - m)) : 0.f;
    for (int off = 16; off; off >>= 1) ss += __shfl_xor(ss, off, 64);
    float lg = logf(ss);
    if (act) {
        float2 o;
        o.x = v0 - m - lg;
        o.y = v1 - m - lg;
        ((float2*)out)[(size_t)wid * 20 + lane] = o;
    }
}

// per-block column partial sums/sumsq over bf16 h (deterministic)
__global__ __launch_bounds__(256) void stats_k(const uint32* __restrict__ h,
                                               float* __restrict__ psum,
                                               float* __restrict__ psq, int n) {
    int c2 = threadIdx.x & 63;
    int g = threadIdx.x >> 6;
    float s0 = 0.f, s1 = 0.f, q0 = 0.f, q1 = 0.f;
    for (int r = blockIdx.x * 4 + g; r < n; r += gridDim.x * 4) {
        uint32 u = h[(size_t)r * 64 + c2];
        float a = bl(u), b = bh(u);
        s0 += a;
        s1 += b;
        q0 += a * a;
        q1 += b * b;
    }
    __shared__ float L[4][256];
    L[0][threadIdx.x] = s0;
    L[1][threadIdx.x] = s1;
    L[2][threadIdx.x] = q0;
    L[3][threadIdx.x] = q1;
    __syncthreads();
    if (threadIdx.x < 64) {
        int c = threadIdx.x;
        float S0 = 0, S1 = 0, Q0 = 0, Q1 = 0;
#pragma unroll
        for (int gg = 0; gg < 4; gg++) {
            S0 += L[0][gg * 64 + c];
            S1 += L[1][gg * 64 + c];
            Q0 += L[2][gg * 64 + c];
            Q1 += L[3][gg * 64 + c];
        }
        psum[blockIdx.x * 128 + 2 * c] = S0;
        psum[blockIdx.x * 128 + 2 * c + 1] = S1;
        psq[blockIdx.x * 128 + 2 * c] = Q0;
        psq[blockIdx.x * 128 + 2 * c + 1] = Q1;
    }
}

__global__ void finalize_stats(const float* __restrict__ psum,
                               const float* __restrict__ psq,
                               const float* __restrict__ g,
                               const float* __restrict__ be,
                               float* __restrict__ scale,
                               float* __restrict__ shift, int nb, float invN) {
    int c = threadIdx.x;  // 128 threads
    float s = 0.f, q = 0.f;
    for (int b = 0; b < nb; b++) {
        s += psum[b * 128 + c];
        q += psq[b * 128 + c];
    }
    float mu = s * invN;
    float var = q * invN - mu * mu;
    float sc = g[c] * rsqrtf(var + 1e-5f);
    scale[c] = sc;
    shift[c] = be[c] - mu * sc;
}

extern "C" void kernel_launch(void* const* d_in, const int* in_sizes, int n_in,
                              void* d_out, int out_size, void* d_ws, size_t ws_size,
                              hipStream_t stream) {
    const float* x   = (const float*)d_in[0];
    const float* W1  = (const float*)d_in[1];
    const float* b1  = (const float*)d_in[2];
    const float* W2  = (const float*)d_in[3];
    const float* b2  = (const float*)d_in[4];
    const float* W3  = (const float*)d_in[5];
    const float* b3  = (const float*)d_in[6];
    const float* g1  = (const float*)d_in[7];
    const float* be1 = (const float*)d_in[8];
    const float* g2  = (const float*)d_in[9];
    const float* be2 = (const float*)d_in[10];
    const int*   ei  = (const int*)d_in[11];

    int n = in_sizes[0] / 128;
    int E = in_sizes[11] / 2;
    const int* src = ei;
    const int* dst = ei + E;

    char* p = (char*)d_ws;
    size_t off = 0;
    auto alloc = [&](size_t bytes) -> void* {
        off = (off + 255) & ~(size_t)255;
        void* r = p + off;
        off += bytes;
        return r;
    };
    uint32* hA    = (uint32*)alloc((size_t)n * 64 * 4);   // n x 128 bf16
    uint32* hB    = (uint32*)alloc((size_t)n * 64 * 4);
    float* dinv   = (float*)alloc((size_t)n * 4);
    int*   cnt    = (int*)alloc((size_t)2 * n * 4);
    int*   cursor = cnt + n;
    int*   offs   = (int*)alloc((size_t)(n + 1) * 4);
    int*   bsums  = (int*)alloc(512 * 4);
    int*   bscan  = (int*)alloc(512 * 4);
    int*   csr    = (int*)alloc((size_t)E * 4);
    float* psum   = (float*)alloc(256 * 128 * 4);
    float* psq    = (float*)alloc(256 * 128 * 4);
    float* scale  = (float*)alloc(128 * 4);
    float* shift  = (float*)alloc(128 * 4);
    (void)ws_size;

    int nbE = (E + 255) / 256;
    int nbN = (n + 255) / 256;
    int gGemm = (n + 31) / 32;
    int gAgg = (n * 64 + 255) / 256;
    float invN = 1.0f / (float)n;

    hipMemsetAsync(cnt, 0, (size_t)2 * n * 4, stream);

    count_deg<<<nbE, 256, 0, stream>>>(dst, cnt, E);
    compute_dinv<<<nbN, 256, 0, stream>>>(cnt, dinv, n);
    scan1<<<nbN, 256, 0, stream>>>(cnt, offs, bsums, n);
    scan2<<<1, 512, 0, stream>>>(bsums, bscan, nbN);
    scan3<<<nbN, 256, 0, stream>>>(offs, bscan, n, E);
    fill_csr<<<nbE, 256, 0, stream>>>(src, dst, offs, cursor, csr, E);

    // layer 1
    gemm128_k<false, false><<<gGemm, 256, 0, stream>>>(x, W1, hA, dinv, n, nullptr, nullptr);
    agg128<<<gAgg, 256, 0, stream>>>(hA, csr, offs, dinv, b1, hB, n);
    stats_k<<<256, 256, 0, stream>>>(hB, psum, psq, n);
    finalize_stats<<<1, 128, 0, stream>>>(psum, psq, g1, be1, scale, shift, 256, invN);

    // layer 2
    gemm128_k<true, true><<<gGemm, 256, 0, stream>>>(hB, W2, hA, dinv, n, scale, shift);
    agg128<<<gAgg, 256, 0, stream>>>(hA, csr, offs, dinv, b2, hB, n);
    stats_k<<<256, 256, 0, stream>>>(hB, psum, psq, n);
    finalize_stats<<<1, 128, 0, stream>>>(psum, psq, g2, be2, scale, shift, 256, invN);

    // layer 3 + log_softmax
    gemm40<<<gGemm, 256, 0, stream>>>((const ushort16*)hB, W3, hA, dinv, n, scale, shift);
    agg40_lsm<<<gAgg, 256, 0, stream>>>(hA, csr, offs, dinv, b3, (float*)d_out, n);
}

// Round 4
// 668.790 us; speedup vs baseline: 1.6011x; 1.3772x over previous
//
#include <hip/hip_runtime.h>
#include <cstdint>
#include <cstddef>

// ---------------------------------------------------------------------------
// GCN 3-layer forward. bf16 storage + bf16 MFMA gemms, f32 accumulation.
// gemm epilogue pre-scales rows by dinv[row] so aggregation is a pure sum:
//   out[d] = dinv[d] * (sum_{s in N(d)} hs[s] + hs[d]) + bias
// ---------------------------------------------------------------------------

typedef unsigned int uint32;
typedef __attribute__((ext_vector_type(8))) short bf16x8;
typedef __attribute__((ext_vector_type(4))) float f32x4;

__device__ inline float bl(uint32 u) { uint32 v = u << 16; return __builtin_bit_cast(float, v); }
__device__ inline float bh(uint32 u) { uint32 v = u & 0xffff0000u; return __builtin_bit_cast(float, v); }
__device__ inline uint32 f2b(float f) {   // RNE f32 -> bf16 bits
    uint32 u = __builtin_bit_cast(uint32, f);
    return (u + 0x7fffu + ((u >> 16) & 1u)) >> 16;
}
__device__ inline uint32 pack2(float x, float y) { return f2b(x) | (f2b(y) << 16); }

#define MFMA16(a, b, c) __builtin_amdgcn_mfma_f32_16x16x32_bf16(a, b, c, 0, 0, 0)

// ---------------- setup kernels ----------------

__global__ __launch_bounds__(256) void count_deg(const int* __restrict__ dst,
                                                 int* __restrict__ cnt, int E) {
    int e = blockIdx.x * 256 + threadIdx.x;
    if (e < E) atomicAdd(&cnt[dst[e]], 1);
}

__global__ __launch_bounds__(256) void compute_dinv(const int* __restrict__ cnt,
                                                    float* __restrict__ dinv, int n) {
    int i = blockIdx.x * 256 + threadIdx.x;
    if (i < n) dinv[i] = rsqrtf((float)(cnt[i] + 1));  // +1 self loop
}

__global__ __launch_bounds__(256) void scan1(const int* __restrict__ cnt,
                                             int* __restrict__ offs,
                                             int* __restrict__ bsums, int n) {
    __shared__ int s[256];
    int tx = threadIdx.x;
    int i = blockIdx.x * 256 + tx;
    int v = (i < n) ? cnt[i] : 0;
    s[tx] = v;
    __syncthreads();
    for (int off = 1; off < 256; off <<= 1) {
        int t = (tx >= off) ? s[tx - off] : 0;
        __syncthreads();
        s[tx] += t;
        __syncthreads();
    }
    if (i < n) offs[i] = s[tx] - v;
    if (tx == 255) bsums[blockIdx.x] = s[255];
}

__global__ __launch_bounds__(512) void scan2(const int* __restrict__ bsums,
                                             int* __restrict__ bscan, int nb) {
    __shared__ int s[512];
    int tx = threadIdx.x;
    int v = (tx < nb) ? bsums[tx] : 0;
    s[tx] = v;
    __syncthreads();
    for (int off = 1; off < 512; off <<= 1) {
        int t = (tx >= off) ? s[tx - off] : 0;
        __syncthreads();
        s[tx] += t;
        __syncthreads();
    }
    if (tx < nb) bscan[tx] = s[tx] - v;
}

__global__ __launch_bounds__(256) void scan3(int* __restrict__ offs,
                                             const int* __restrict__ bscan,
                                             int n, int E) {
    int i = blockIdx.x * 256 + threadIdx.x;
    if (i < n) offs[i] += bscan[blockIdx.x];
    if (i == 0) offs[n] = E;
}

__global__ __launch_bounds__(256) void fill_csr(const int* __restrict__ src,
                                                const int* __restrict__ dst,
                                                const int* __restrict__ offs,
                                                int* __restrict__ cursor,
                                                int* __restrict__ csr, int E) {
    int e = blockIdx.x * 256 + threadIdx.x;
    if (e < E) {
        int d = dst[e];
        int pos = offs[d] + atomicAdd(&cursor[d], 1);
        csr[pos] = src[e];
    }
}

// W (f32 [K][Ncol]) -> WT (bf16 [Nout][128]), Ncol<=Nout (pad cols with 0)
__global__ __launch_bounds__(256) void wconv(const float* __restrict__ W1,
                                             const float* __restrict__ W2,
                                             const float* __restrict__ W3,
                                             unsigned short* __restrict__ wt1,
                                             unsigned short* __restrict__ wt2,
                                             unsigned short* __restrict__ wt3) {
    int b = blockIdx.x, tx = threadIdx.x;
    if (b < 2) {
        const float* S = b ? W2 : W1;
        unsigned short* D = b ? wt2 : wt1;
        for (int i = tx; i < 128 * 128; i += 256) {
            int k = i >> 7, nn = i & 127;
            D[nn * 128 + k] = (unsigned short)f2b(S[i]);
        }
    } else {
        for (int i = tx; i < 48 * 128; i += 256) {
            int k = i / 48, nn = i - k * 48;
            float v = (nn < 40) ? W3[k * 40 + nn] : 0.f;
            wt3[nn * 128 + k] = (unsigned short)f2b(v);
        }
    }
}

// ---------------- MFMA gemms ----------------
// LDS chunk addressing: element off = r*128 + ((kb ^ (r&7))<<3), kb = 16B block

// C[r][c] (bf16 packed pairs, n x 128) = bnrelu(A[r][:]) @ W * dinv[r]
template <bool ABF16, bool BN>
__global__ __launch_bounds__(256) void gemm128m(const void* __restrict__ Av,
                                                const unsigned short* __restrict__ WT,
                                                uint32* __restrict__ C,
                                                const float* __restrict__ dinv, int n,
                                                const float* __restrict__ scale,
                                                const float* __restrict__ shift) {
    __shared__ unsigned short Wls[128 * 128];
    __shared__ unsigned short Als[128 * 128];
    int tx = threadIdx.x;
    int row0 = blockIdx.x * 128;
    {   // stage W: 2048 uint4 chunks
        const uint4* srcW = (const uint4*)WT;
#pragma unroll
        for (int i = 0; i < 8; i++) {
            int cid = tx + 256 * i;
            int nr = cid >> 4, kb = cid & 15;
            uint4 u = srcW[cid];
            *(uint4*)&Wls[nr * 128 + ((kb ^ (nr & 7)) << 3)] = u;
        }
    }
    int kb = tx & 15;
    if (ABF16) {
        const uint4* src = (const uint4*)Av;
        float4 sA, sB, hA_, hB_;
        if (BN) {
            sA = ((const float4*)scale)[kb * 2];
            sB = ((const float4*)scale)[kb * 2 + 1];
            hA_ = ((const float4*)shift)[kb * 2];
            hB_ = ((const float4*)shift)[kb * 2 + 1];
        }
#pragma unroll
        for (int i = 0; i < 8; i++) {
            int r = (tx >> 4) + 16 * i;
            int gr = row0 + r;
            if (gr >= n) gr = n - 1;
            uint4 u = src[(size_t)gr * 16 + kb];
            if (BN) {
                uint4 o;
                o.x = pack2(fmaxf(0.f, bl(u.x) * sA.x + hA_.x), fmaxf(0.f, bh(u.x) * sA.y + hA_.y));
                o.y = pack2(fmaxf(0.f, bl(u.y) * sA.z + hA_.z), fmaxf(0.f, bh(u.y) * sA.w + hA_.w));
                o.z = pack2(fmaxf(0.f, bl(u.z) * sB.x + hB_.x), fmaxf(0.f, bh(u.z) * sB.y + hB_.y));
                o.w = pack2(fmaxf(0.f, bl(u.w) * sB.z + hB_.z), fmaxf(0.f, bh(u.w) * sB.w + hB_.w));
                u = o;
            }
            *(uint4*)&Als[r * 128 + ((kb ^ (r & 7)) << 3)] = u;
        }
    } else {
        const float4* src = (const float4*)Av;
#pragma unroll
        for (int i = 0; i < 8; i++) {
            int r = (tx >> 4) + 16 * i;
            int gr = row0 + r;
            if (gr >= n) gr = n - 1;
            float4 a = src[(size_t)gr * 32 + kb * 2];
            float4 b = src[(size_t)gr * 32 + kb * 2 + 1];
            uint4 u;
            u.x = pack2(a.x, a.y);
            u.y = pack2(a.z, a.w);
            u.z = pack2(b.x, b.y);
            u.w = pack2(b.z, b.w);
            *(uint4*)&Als[r * 128 + ((kb ^ (r & 7)) << 3)] = u;
        }
    }
    __syncthreads();

    int w = tx >> 6, lane = tx & 63;
    int r0 = w * 32;
    int lrow = lane & 15, lkg = lane >> 4;
    f32x4 acc[2][8];
#pragma unroll
    for (int rt = 0; rt < 2; rt++)
#pragma unroll
        for (int nt = 0; nt < 8; nt++) acc[rt][nt] = (f32x4){0.f, 0.f, 0.f, 0.f};
#pragma unroll
    for (int ks = 0; ks < 4; ks++) {
        int kbl = ks * 4 + lkg;
        int r = r0 + lrow;
        bf16x8 a0 = *(const bf16x8*)&Als[r * 128 + ((kbl ^ (r & 7)) << 3)];
        int r2 = r0 + 16 + lrow;
        bf16x8 a1 = *(const bf16x8*)&Als[r2 * 128 + ((kbl ^ (r2 & 7)) << 3)];
#pragma unroll
        for (int nt = 0; nt < 8; nt++) {
            int nr = nt * 16 + lrow;
            bf16x8 b = *(const bf16x8*)&Wls[nr * 128 + ((kbl ^ (nr & 7)) << 3)];
            acc[0][nt] = MFMA16(a0, b, acc[0][nt]);
            acc[1][nt] = MFMA16(a1, b, acc[1][nt]);
        }
    }
    // epilogue: per-wave LDS bounce (wave's own A slice, 8KB), then packed store
    float* SL = (float*)&Als[w * 4096];
#pragma unroll
    for (int rt = 0; rt < 2; rt++) {
#pragma unroll
        for (int nt = 0; nt < 8; nt++)
#pragma unroll
            for (int j = 0; j < 4; j++)
                SL[(lkg * 4 + j) * 128 + nt * 16 + lrow] = acc[rt][nt][j];
#pragma unroll
        for (int i = 0; i < 8; i++) {
            int rloc = i * 2 + (lane >> 5);
            int gr = row0 + r0 + rt * 16 + rloc;
            int cq = lane & 31;
            if (gr < n) {
                float dv = dinv[gr];
                float4 v = *(float4*)&SL[rloc * 128 + cq * 4];
                uint2 o;
                o.x = pack2(v.x * dv, v.y * dv);
                o.y = pack2(v.z * dv, v.w * dv);
                *(uint2*)&C[(size_t)gr * 64 + cq * 2] = o;
            }
        }
        if (rt == 0) __builtin_amdgcn_s_waitcnt(0);  // drain before SL reuse
    }
}

// C[n x 40] bf16 = bnrelu(A bf16) @ W3 * dinv[r]  (N padded to 48 in WT3)
__global__ __launch_bounds__(256) void gemm40m(const uint32* __restrict__ A,
                                               const unsigned short* __restrict__ WT,
                                               unsigned short* __restrict__ C,
                                               const float* __restrict__ dinv, int n,
                                               const float* __restrict__ scale,
                                               const float* __restrict__ shift) {
    __shared__ unsigned short Wls[48 * 128];
    __shared__ unsigned short Als[128 * 128];
    int tx = threadIdx.x;
    int row0 = blockIdx.x * 128;
    {
        const uint4* srcW = (const uint4*)WT;
#pragma unroll
        for (int i = 0; i < 3; i++) {
            int cid = tx + 256 * i;
            int nr = cid >> 4, kb = cid & 15;
            uint4 u = srcW[cid];
            *(uint4*)&Wls[nr * 128 + ((kb ^ (nr & 7)) << 3)] = u;
        }
    }
    int kb = tx & 15;
    {
        const uint4* src = (const uint4*)A;
        float4 sA = ((const float4*)scale)[kb * 2];
        float4 sB = ((const float4*)scale)[kb * 2 + 1];
        float4 hA_ = ((const float4*)shift)[kb * 2];
        float4 hB_ = ((const float4*)shift)[kb * 2 + 1];
#pragma unroll
        for (int i = 0; i < 8; i++) {
            int r = (tx >> 4) + 16 * i;
            int gr = row0 + r;
            if (gr >= n) gr = n - 1;
            uint4 u = src[(size_t)gr * 16 + kb];
            uint4 o;
            o.x = pack2(fmaxf(0.f, bl(u.x) * sA.x + hA_.x), fmaxf(0.f, bh(u.x) * sA.y + hA_.y));
            o.y = pack2(fmaxf(0.f, bl(u.y) * sA.z + hA_.z), fmaxf(0.f, bh(u.y) * sA.w + hA_.w));
            o.z = pack2(fmaxf(0.f, bl(u.z) * sB.x + hB_.x), fmaxf(0.f, bh(u.z) * sB.y + hB_.y));
            o.w = pack2(fmaxf(0.f, bl(u.w) * sB.z + hB_.z), fmaxf(0.f, bh(u.w) * sB.w + hB_.w));
            *(uint4*)&Als[r * 128 + ((kb ^ (r & 7)) << 3)] = o;
        }
    }
    __syncthreads();

    int w = tx >> 6, lane = tx & 63;
    int r0 = w * 32;
    int lrow = lane & 15, lkg = lane >> 4;
    f32x4 acc[2][3];
#pragma unroll
    for (int rt = 0; rt < 2; rt++)
#pragma unroll
        for (int nt = 0; nt < 3; nt++) acc[rt][nt] = (f32x4){0.f, 0.f, 0.f, 0.f};
#pragma unroll
    for (int ks = 0; ks < 4; ks++) {
        int kbl = ks * 4 + lkg;
        int r = r0 + lrow;
        bf16x8 a0 = *(const bf16x8*)&Als[r * 128 + ((kbl ^ (r & 7)) << 3)];
        int r2 = r0 + 16 + lrow;
        bf16x8 a1 = *(const bf16x8*)&Als[r2 * 128 + ((kbl ^ (r2 & 7)) << 3)];
#pragma unroll
        for (int nt = 0; nt < 3; nt++) {
            int nr = nt * 16 + lrow;
            bf16x8 b = *(const bf16x8*)&Wls[nr * 128 + ((kbl ^ (nr & 7)) << 3)];
            acc[0][nt] = MFMA16(a0, b, acc[0][nt]);
            acc[1][nt] = MFMA16(a1, b, acc[1][nt]);
        }
    }
#pragma unroll
    for (int rt = 0; rt < 2; rt++)
#pragma unroll
        for (int j = 0; j < 4; j++) {
            int gr = row0 + r0 + rt * 16 + lkg * 4 + j;
            if (gr < n) {
                float dv = dinv[gr];
#pragma unroll
                for (int nt = 0; nt < 3; nt++) {
                    int col = nt * 16 + lrow;
                    if (col < 40)
                        C[(size_t)gr * 40 + col] = (unsigned short)f2b(acc[rt][nt][j] * dv);
                }
            }
        }
}

// ---------------- aggregation ----------------

// out[d] = pack( dinv[d] * (sum_{s in N(d)} hs[s] + hs[d]) + bias ), 128 bf16 cols
__global__ __launch_bounds__(256) void agg128(const uint32* __restrict__ h,
                                              const int* __restrict__ csr,
                                              const int* __restrict__ offs,
                                              const float* __restrict__ dinv,
                                              const float* __restrict__ bias,
                                              uint32* __restrict__ out, int n) {
    int wid = (blockIdx.x * 256 + threadIdx.x) >> 6;
    int lane = threadIdx.x & 63;
    if (wid >= n) return;
    uint32 self = h[(size_t)wid * 64 + lane];
    float ax0 = bl(self), ay0 = bh(self);
    float ax1 = 0.f, ay1 = 0.f;
    int e0 = offs[wid], e1 = offs[wid + 1];
    int e = e0;
    while (e < e1) {
        int cnt = e1 - e;
        if (cnt > 64) cnt = 64;
        int sl = (lane < cnt) ? csr[e + lane] : 0;
        int j = 0;
        for (; j + 3 < cnt; j += 4) {
            int s0 = __shfl(sl, j, 64);
            int s1 = __shfl(sl, j + 1, 64);
            int s2 = __shfl(sl, j + 2, 64);
            int s3 = __shfl(sl, j + 3, 64);
            uint32 u0 = h[(size_t)s0 * 64 + lane];
            uint32 u1 = h[(size_t)s1 * 64 + lane];
            uint32 u2 = h[(size_t)s2 * 64 + lane];
            uint32 u3 = h[(size_t)s3 * 64 + lane];
            ax0 += bl(u0); ay0 += bh(u0);
            ax1 += bl(u1); ay1 += bh(u1);
            ax0 += bl(u2); ay0 += bh(u2);
            ax1 += bl(u3); ay1 += bh(u3);
        }
        for (; j < cnt; j++) {
            int s = __shfl(sl, j, 64);
            uint32 u = h[(size_t)s * 64 + lane];
            ax0 += bl(u); ay0 += bh(u);
        }
        e += cnt;
    }
    float ax = ax0 + ax1, ay = ay0 + ay1;
    float di = dinv[wid];
    float2 b = ((const float2*)bias)[lane];
    out[(size_t)wid * 64 + lane] = pack2(ax * di + b.x, ay * di + b.y);
}

// 40-col aggregation + bias + log_softmax.  3 lane-groups x 20 cols; FULLY
// CONVERGENT: uniform trip count, every lane executes every __shfl with a
// clamped source; only the dependent loads are predicated.
__global__ __launch_bounds__(256) void agg40_lsm(const uint32* __restrict__ h,
                                                 const int* __restrict__ csr,
                                                 const int* __restrict__ offs,
                                                 const float* __restrict__ dinv,
                                                 const float* __restrict__ bias,
                                                 float* __restrict__ out, int n) {
    int wid = (blockIdx.x * 256 + threadIdx.x) >> 6;
    int lane = threadIdx.x & 63;
    if (wid >= n) return;
    int grp = lane / 20;              // 0,1,2 work; grp==3 (lanes 60-63) idle
    int c = lane - grp * 20;
    bool work = grp < 3;
    float vx = 0.f, vy = 0.f;
    if (grp == 0) {                   // self term once
        uint32 u = h[(size_t)wid * 20 + c];
        vx = bl(u);
        vy = bh(u);
    }
    int e0 = offs[wid], e1 = offs[wid + 1];
    int e = e0;
    while (e < e1) {                  // wave-uniform
        int cnt = e1 - e;
        if (cnt > 64) cnt = 64;
        int sl = (lane < cnt) ? csr[e + lane] : 0;
        int nIt = (cnt + 5) / 6;      // wave-uniform trip count
        for (int it = 0; it < nIt; it++) {
            int j0 = it * 6 + grp;
            int j1 = j0 + 3;
            int s0 = __shfl(sl, (j0 < cnt) ? j0 : 0, 64);   // convergent
            int s1 = __shfl(sl, (j1 < cnt) ? j1 : 0, 64);   // convergent
            if (work && j0 < cnt) {
                uint32 u = h[(size_t)s0 * 20 + c];
                vx += bl(u); vy += bh(u);
            }
            if (work && j1 < cnt) {
                uint32 u = h[(size_t)s1 * 20 + c];
                vx += bl(u); vy += bh(u);
            }
        }
        e += cnt;
    }
    // combine the 3 groups into lanes 0..19 (sources always active here)
    float t1x = __shfl(vx, (lane + 20) & 63, 64), t2x = __shfl(vx, (lane + 40) & 63, 64);
    float t1y = __shfl(vy, (lane + 20) & 63, 64), t2y = __shfl(vy, (lane + 40) & 63, 64);
    vx += t1x + t2x;
    vy += t1y + t2y;
    float di = dinv[wid];
    float v0 = -1e30f, v1 = -1e30f;
    if (lane < 20) {
        v0 = vx * di + bias[2 * lane];
        v1 = vy * di + bias[2 * lane + 1];
    }
    float m = fmaxf(v0, v1);
    for (int off = 16; off; off >>= 1) m = fmaxf(m, __shfl_xor(m, off, 64));
    float ss = (lane < 20) ? (expf(v0 - m) + expf(v1 - m)) : 0.f;
    for (int off = 16; off; off >>= 1) ss += __shfl_xor(ss, off, 64);
    float lg = logf(ss);
    if (lane < 20) {
        float2 o;
        o.x = v0 - m - lg;
        o.y = v1 - m - lg;
        ((float2*)out)[(size_t)wid * 20 + lane] = o;
    }
}

// ---------------- BN stats ----------------

__global__ __launch_bounds__(256) void stats_k(const uint32* __restrict__ h,
                                               float* __restrict__ psum,
                                               float* __restrict__ psq, int n) {
    int c2 = threadIdx.x & 63;
    int g = threadIdx.x >> 6;
    float s0 = 0.f, s1 = 0.f, q0 = 0.f, q1 = 0.f;
    for (int r = blockIdx.x * 4 + g; r < n; r += gridDim.x * 4) {
        uint32 u = h[(size_t)r * 64 + c2];
        float a = bl(u), b = bh(u);
        s0 += a; s1 += b;
        q0 += a * a; q1 += b * b;
    }
    __shared__ float L[4][256];
    L[0][threadIdx.x] = s0;
    L[1][threadIdx.x] = s1;
    L[2][threadIdx.x] = q0;
    L[3][threadIdx.x] = q1;
    __syncthreads();
    if (threadIdx.x < 64) {
        int c = threadIdx.x;
        float S0 = 0, S1 = 0, Q0 = 0, Q1 = 0;
#pragma unroll
        for (int gg = 0; gg < 4; gg++) {
            S0 += L[0][gg * 64 + c];
            S1 += L[1][gg * 64 + c];
            Q0 += L[2][gg * 64 + c];
            Q1 += L[3][gg * 64 + c];
        }
        psum[blockIdx.x * 128 + 2 * c] = S0;
        psum[blockIdx.x * 128 + 2 * c + 1] = S1;
        psq[blockIdx.x * 128 + 2 * c] = Q0;
        psq[blockIdx.x * 128 + 2 * c + 1] = Q1;
    }
}

__global__ void finalize_stats(const float* __restrict__ psum,
                               const float* __restrict__ psq,
                               const float* __restrict__ g,
                               const float* __restrict__ be,
                               float* __restrict__ scale,
                               float* __restrict__ shift, int nb, float invN) {
    int c = threadIdx.x;  // 128 threads
    float s = 0.f, q = 0.f;
    for (int b = 0; b < nb; b++) {
        s += psum[b * 128 + c];
        q += psq[b * 128 + c];
    }
    float mu = s * invN;
    float var = q * invN - mu * mu;
    float sc = g[c] * rsqrtf(var + 1e-5f);
    scale[c] = sc;
    shift[c] = be[c] - mu * sc;
}

extern "C" void kernel_launch(void* const* d_in, const int* in_sizes, int n_in,
                              void* d_out, int out_size, void* d_ws, size_t ws_size,
                              hipStream_t stream) {
    const float* x   = (const float*)d_in[0];
    const float* W1  = (const float*)d_in[1];
    const float* b1  = (const float*)d_in[2];
    const float* W2  = (const float*)d_in[3];
    const float* b2  = (const float*)d_in[4];
    const float* W3  = (const float*)d_in[5];
    const float* b3  = (const float*)d_in[6];
    const float* g1  = (const float*)d_in[7];
    const float* be1 = (const float*)d_in[8];
    const float* g2  = (const float*)d_in[9];
    const float* be2 = (const float*)d_in[10];
    const int*   ei  = (const int*)d_in[11];

    int n = in_sizes[0] / 128;
    int E = in_sizes[11] / 2;
    const int* src = ei;
    const int* dst = ei + E;

    char* p = (char*)d_ws;
    size_t off = 0;
    auto alloc = [&](size_t bytes) -> void* {
        off = (off + 255) & ~(size_t)255;
        void* r = p + off;
        off += bytes;
        return r;
    };
    uint32* hA    = (uint32*)alloc((size_t)n * 64 * 4);   // n x 128 bf16
    uint32* hB    = (uint32*)alloc((size_t)n * 64 * 4);
    float* dinv   = (float*)alloc((size_t)n * 4);
    int*   cnt    = (int*)alloc((size_t)2 * n * 4);
    int*   cursor = cnt + n;
    int*   offs   = (int*)alloc((size_t)(n + 1) * 4);
    int*   bsums  = (int*)alloc(512 * 4);
    int*   bscan  = (int*)alloc(512 * 4);
    int*   csr    = (int*)alloc((size_t)E * 4);
    float* psum   = (float*)alloc(64 * 128 * 4);
    float* psq    = (float*)alloc(64 * 128 * 4);
    float* scale  = (float*)alloc(128 * 4);
    float* shift  = (float*)alloc(128 * 4);
    unsigned short* wt1 = (unsigned short*)alloc(128 * 128 * 2);
    unsigned short* wt2 = (unsigned short*)alloc(128 * 128 * 2);
    unsigned short* wt3 = (unsigned short*)alloc(48 * 128 * 2);
    (void)ws_size;

    int nbE = (E + 255) / 256;
    int nbN = (n + 255) / 256;
    int gG = (n + 127) / 128;           // 782 mfma-gemm blocks
    int gAgg = (n * 64 + 255) / 256;
    float invN = 1.0f / (float)n;

    hipMemsetAsync(cnt, 0, (size_t)2 * n * 4, stream);

    wconv<<<3, 256, 0, stream>>>(W1, W2, W3, wt1, wt2, wt3);
    count_deg<<<nbE, 256, 0, stream>>>(dst, cnt, E);
    compute_dinv<<<nbN, 256, 0, stream>>>(cnt, dinv, n);
    scan1<<<nbN, 256, 0, stream>>>(cnt, offs, bsums, n);
    scan2<<<1, 512, 0, stream>>>(bsums, bscan, nbN);
    scan3<<<nbN, 256, 0, stream>>>(offs, bscan, n, E);
    fill_csr<<<nbE, 256, 0, stream>>>(src, dst, offs, cursor, csr, E);

    // layer 1
    gemm128m<false, false><<<gG, 256, 0, stream>>>(x, wt1, hA, dinv, n, nullptr, nullptr);
    agg128<<<gAgg, 256, 0, stream>>>(hA, csr, offs, dinv, b1, hB, n);
    stats_k<<<64, 256, 0, stream>>>(hB, psum, psq, n);
    finalize_stats<<<1, 128, 0, stream>>>(psum, psq, g1, be1, scale, shift, 64, invN);

    // layer 2
    gemm128m<true, true><<<gG, 256, 0, stream>>>(hB, wt2, hA, dinv, n, scale, shift);
    agg128<<<gAgg, 256, 0, stream>>>(hA, csr, offs, dinv, b2, hB, n);
    stats_k<<<64, 256, 0, stream>>>(hB, psum, psq, n);
    finalize_stats<<<1, 128, 0, stream>>>(psum, psq, g2, be2, scale, shift, 64, invN);

    // layer 3 + log_softmax
    gemm40m<<<gG, 256, 0, stream>>>(hB, wt3, (unsigned short*)hA, dinv, n, scale, shift);
    agg40_lsm<<<gAgg, 256, 0, stream>>>(hA, csr, offs, dinv, b3, (float*)d_out, n);
}